// Round 1
// baseline (1402.673 us; speedup 1.0000x reference)
//
#include <hip/hip_runtime.h>

#define TT     32
#define HW     4096           // 64*64
#define LROW   67             // 66 cols + 1 pad
#define LPLANE (6 * LROW)     // 6 halo rows per cin
#define SXSZ   (3 * LPLANE)   // 1206 floats per plane buffer
#define NSTG   (3 * 6 * 66)   // 1188 staged elements per plane

__device__ __forceinline__ float fsigmoid(float x) {
    return __builtin_amdgcn_rcpf(1.0f + __builtin_amdgcn_exp2f(x * -1.4426950408889634f));
}
__device__ __forceinline__ float ftanh(float x) {
    return 2.0f * __builtin_amdgcn_rcpf(1.0f + __builtin_amdgcn_exp2f(x * -2.8853900817779268f)) - 1.0f;
}
// force a wave-uniform float into an SGPR
__device__ __forceinline__ float sgprf(float v) {
    return __uint_as_float(__builtin_amdgcn_readfirstlane(__float_as_uint(v)));
}

__global__ __launch_bounds__(256, 8) void convqrnn(
    const float* __restrict__ X,    // (4,3,32,64,64)
    const float* __restrict__ Wc,   // (256,3,2,3,3)
    const float* __restrict__ bc,   // (256)
    const float* __restrict__ Wci,  // (64,64,64)
    const float* __restrict__ Wcf,
    const float* __restrict__ Wco,
    float* __restrict__ out)        // (4,64,32,64,64)
{
    __shared__ float sx[2 * SXSZ];     // double-buffered staged plane
    __shared__ float gb[2 * 1024];     // double-buffered gate exchange

    const int tid = threadIdx.x;
    const int h0  = blockIdx.x * 4;    // 16 row-tiles of height 4, full width
    const int co  = blockIdx.y;
    const int b   = blockIdx.z;

    // gate-compute mapping: wave g handles gate g; lane owns 4 consecutive cols
    const int g  = tid >> 6;
    const int l  = tid & 63;
    const int r  = l >> 4;            // 0..3 tile row
    const int c0 = (l & 15) * 4;      // col base (0,4,...,60)

    // recurrence-owner mapping: pixel p = tid (4 rows x 64 cols, row-major)
    const int prow = tid >> 6;
    const int pcol = tid & 63;
    const int opix = (h0 + prow) * 64 + pcol;

    const float wci = Wci[co * HW + opix];
    const float wcf = Wcf[co * HW + opix];
    const float wco = Wco[co * HW + opix];

    // conv weights for (gate g, channel co): 54 floats, wave-uniform -> SGPRs
    float wgt[54];
    {
        const float* __restrict__ wrow = Wc + (size_t)(g * 64 + co) * 54;
        #pragma unroll
        for (int j = 0; j < 54; ++j) wgt[j] = sgprf(wrow[j]);
    }
    const float bg = sgprf(bc[g * 64 + co]);

    // ---- staging precompute: 5 chunks of 256 covering 3x6x66 halo tile ----
    const float* __restrict__ Xb = X + (size_t)b * (3 * TT * HW);
    int  soff[5];
    int  goff[5];
    bool sval[5];
    #pragma unroll
    for (int k = 0; k < 5; ++k) {
        int idx  = tid + k * 256;
        bool inr = (idx < NSTG);
        int idc  = inr ? idx : 0;
        int ci   = idc / 396;              // 6*66
        int rem  = idc - ci * 396;
        int y    = rem / 66;
        int x    = rem - y * 66;
        int gh   = h0 + y - 1;
        int gw   = x - 1;
        bool v   = inr && (gh >= 0) && (gh < 64) && (gw >= 0) && (gw < 64);
        int ghc  = gh < 0 ? 0 : (gh > 63 ? 63 : gh);
        int gwc  = gw < 0 ? 0 : (gw > 63 ? 63 : gw);
        soff[k]  = inr ? (ci * LPLANE + y * LROW + x) : (LROW - 1); // dummy pad slot
        goff[k]  = ci * (TT * HW) + ghc * 64 + gwc;                 // plane 0
        sval[k]  = v;
    }

    // prologue: stage plane t=0 into buffer 0
    #pragma unroll
    for (int k = 0; k < 5; ++k) {
        float v = sval[k] ? Xb[goff[k]] : 0.0f;
        sx[soff[k]] = v;
        goff[k] += HW;                       // -> plane 1
    }

    // output addressing (scalar base + 32-bit vector offset)
    float* __restrict__ outb = out + (size_t)(b * 64 + co) * (TT * HW);
    int ooff = opix;

    float s0c0 = 0.f, s0c1 = 0.f, s0c2 = 0.f, s0c3 = 0.f;  // dt=0 partial carry
    float C = 0.f;

    __syncthreads();   // plane 0 staged

    for (int t = 0; t < TT; ++t) {
        const float* __restrict__ sxb = &sx[(t & 1) * SXSZ];
        float*       __restrict__ gbb = &gb[(t & 1) * 1024];

        // window: 3 cin x 3 rows x 6 cols from LDS (2-way banked -> free)
        float win[3][3][6];
        #pragma unroll
        for (int ci = 0; ci < 3; ++ci)
            #pragma unroll
            for (int kh = 0; kh < 3; ++kh)
                #pragma unroll
                for (int j = 0; j < 6; ++j)
                    win[ci][kh][j] = sxb[ci * LPLANE + (r + kh) * LROW + c0 + j];

        // prefetch next plane's staging values (VMEM overlaps FMAs)
        float stv[5];
        if (t < TT - 1) {                    // uniform branch
            #pragma unroll
            for (int k = 0; k < 5; ++k) {
                stv[k] = sval[k] ? Xb[goff[k]] : 0.0f;
                goff[k] += HW;
            }
        }

        // conv: s1 = dt=1 taps on plane t; n = dt=0 taps on plane t (used at t+1)
        float s10 = bg, s11 = bg, s12 = bg, s13 = bg;
        float n0 = 0.f, n1 = 0.f, n2 = 0.f, n3 = 0.f;
        #pragma unroll
        for (int ci = 0; ci < 3; ++ci)
            #pragma unroll
            for (int kh = 0; kh < 3; ++kh)
                #pragma unroll
                for (int kw = 0; kw < 3; ++kw) {
                    const float wp = wgt[ci * 18 +     kh * 3 + kw];
                    const float wc = wgt[ci * 18 + 9 + kh * 3 + kw];
                    s10 += wc * win[ci][kh][kw + 0];
                    s11 += wc * win[ci][kh][kw + 1];
                    s12 += wc * win[ci][kh][kw + 2];
                    s13 += wc * win[ci][kh][kw + 3];
                    n0  += wp * win[ci][kh][kw + 0];
                    n1  += wp * win[ci][kh][kw + 1];
                    n2  += wp * win[ci][kh][kw + 2];
                    n3  += wp * win[ci][kh][kw + 3];
                }

        float4 gv = make_float4(s10 + s0c0, s11 + s0c1, s12 + s0c2, s13 + s0c3);
        s0c0 = n0; s0c1 = n1; s0c2 = n2; s0c3 = n3;
        *(float4*)&gbb[g * 256 + r * 64 + c0] = gv;

        // commit staged plane t+1 into the other buffer (before the barrier)
        if (t < TT - 1) {                    // uniform branch
            float* __restrict__ sxn = &sx[((t + 1) & 1) * SXSZ];
            #pragma unroll
            for (int k = 0; k < 5; ++k) sxn[soff[k]] = stv[k];
        }

        __syncthreads();   // gates(t) visible; plane t+1 committed

        // recurrence: owner thread per pixel
        const float iv = gbb[tid];
        const float fv = gbb[256 + tid];
        const float gg = gbb[512 + tid];
        const float ov = gbb[768 + tid];
        const float ig = fsigmoid(iv + wci * C);
        const float fg = fsigmoid(fv + wcf * C);
        const float Cn = fg * C + ig * ftanh(gg);
        const float og = fsigmoid(ov + wco * Cn);
        outb[ooff] = og * ftanh(Cn);
        ooff += HW;
        C = Cn;
    }
}

extern "C" void kernel_launch(void* const* d_in, const int* in_sizes, int n_in,
                              void* d_out, int out_size, void* d_ws, size_t ws_size,
                              hipStream_t stream) {
    const float* X   = (const float*)d_in[0];
    const float* Wc  = (const float*)d_in[1];
    const float* bc  = (const float*)d_in[2];
    const float* Wci = (const float*)d_in[3];
    const float* Wcf = (const float*)d_in[4];
    const float* Wco = (const float*)d_in[5];
    float* out = (float*)d_out;

    dim3 grid(16, 64, 4);   // row-tiles, cout, batch
    convqrnn<<<grid, 256, 0, stream>>>(X, Wc, bc, Wci, Wcf, Wco, out);
}

// Round 2
// 462.737 us; speedup vs baseline: 3.0313x; 3.0313x over previous
//
#include <hip/hip_runtime.h>

#define TT     32
#define HW     4096           // 64*64
#define LROW   68             // 66 cols + 2 pad -> rows 16B-aligned (b128 reads)
#define LPLANE (6 * LROW)     // 6 halo rows per cin = 408
#define SXSZ   (3 * LPLANE)   // 1224 floats per plane buffer
#define NSTG   (3 * 6 * 66)   // 1188 staged elements per plane

__device__ __forceinline__ float fsigmoid(float x) {
    return __builtin_amdgcn_rcpf(1.0f + __builtin_amdgcn_exp2f(x * -1.4426950408889634f));
}
__device__ __forceinline__ float ftanh(float x) {
    return 2.0f * __builtin_amdgcn_rcpf(1.0f + __builtin_amdgcn_exp2f(x * -2.8853900817779268f)) - 1.0f;
}
// force a wave-uniform float into an SGPR
__device__ __forceinline__ float sgprf(float v) {
    return __uint_as_float(__builtin_amdgcn_readfirstlane(__float_as_uint(v)));
}

__global__ __launch_bounds__(256, 4) void convqrnn(
    const float* __restrict__ X,    // (4,3,32,64,64)
    const float* __restrict__ Wc,   // (256,3,2,3,3)
    const float* __restrict__ bc,   // (256)
    const float* __restrict__ Wci,  // (64,64,64)
    const float* __restrict__ Wcf,
    const float* __restrict__ Wco,
    float* __restrict__ out)        // (4,64,32,64,64)
{
    __shared__ float sx[2 * SXSZ];     // double-buffered staged plane
    __shared__ float gb[2 * 1024];     // double-buffered gate exchange

    const int tid = threadIdx.x;
    const int h0  = blockIdx.x * 4;    // 16 row-tiles of height 4, full width
    const int co  = blockIdx.y;
    const int b   = blockIdx.z;

    // gate-compute mapping: wave g handles gate g; lane owns 4 consecutive cols
    const int g  = tid >> 6;
    const int l  = tid & 63;
    const int r  = l >> 4;            // 0..3 tile row
    const int c0 = (l & 15) * 4;      // col base (0,4,...,60)

    // recurrence-owner mapping: pixel p = tid (4 rows x 64 cols, row-major)
    const int prow = tid >> 6;
    const int pcol = tid & 63;
    const int opix = (h0 + prow) * 64 + pcol;

    const float wci = Wci[co * HW + opix];
    const float wcf = Wcf[co * HW + opix];
    const float wco = Wco[co * HW + opix];

    // conv weights for (gate g, channel co): 54 floats, wave-uniform -> SGPRs
    float wgt[54];
    {
        const float* __restrict__ wrow = Wc + (size_t)(g * 64 + co) * 54;
        #pragma unroll
        for (int j = 0; j < 54; ++j) wgt[j] = sgprf(wrow[j]);
    }
    const float bg = sgprf(bc[g * 64 + co]);

    // ---- staging precompute: 5 chunks of 256 covering 3x6x66 halo tile ----
    const float* __restrict__ Xb = X + (size_t)b * (3 * TT * HW);
    int soff[5];
    int goff[5];
    int svmask = 0;
    #pragma unroll
    for (int k = 0; k < 5; ++k) {
        int idx  = tid + k * 256;
        bool inr = (idx < NSTG);
        int idc  = inr ? idx : 0;
        int ci   = idc / 396;              // 6*66
        int rem  = idc - ci * 396;
        int y    = rem / 66;
        int x    = rem - y * 66;
        int gh   = h0 + y - 1;
        int gw   = x - 1;
        bool v   = inr && (gh >= 0) && (gh < 64) && (gw >= 0) && (gw < 64);
        int ghc  = gh < 0 ? 0 : (gh > 63 ? 63 : gh);
        int gwc  = gw < 0 ? 0 : (gw > 63 ? 63 : gw);
        soff[k]  = inr ? (ci * LPLANE + y * LROW + x) : (LROW - 1); // dummy pad slot
        goff[k]  = ci * (TT * HW) + ghc * 64 + gwc;                 // plane 0
        svmask  |= (v ? 1 : 0) << k;
    }

    // prologue: stage plane t=0 into buffer 0
    #pragma unroll
    for (int k = 0; k < 5; ++k) {
        float v = ((svmask >> k) & 1) ? Xb[goff[k]] : 0.0f;
        sx[soff[k]] = v;
        goff[k] += HW;                       // -> plane 1
    }

    // output addressing (scalar base + 32-bit vector offset)
    float* __restrict__ outb = out + (size_t)(b * 64 + co) * (TT * HW);
    int ooff = opix;

    float s0c0 = 0.f, s0c1 = 0.f, s0c2 = 0.f, s0c3 = 0.f;  // dt=0 partial carry
    float C = 0.f;

    __syncthreads();   // plane 0 staged

    for (int t = 0; t < TT; ++t) {
        const float* __restrict__ sxb = &sx[(t & 1) * SXSZ];
        float*       __restrict__ gbb = &gb[(t & 1) * 1024];

        // window: 3 cin x 3 rows x 6 cols from LDS; rows 16B-aligned -> b128+b64
        float win[3][3][6];
        #pragma unroll
        for (int ci = 0; ci < 3; ++ci)
            #pragma unroll
            for (int kh = 0; kh < 3; ++kh) {
                const float* rowp = &sxb[ci * LPLANE + (r + kh) * LROW + c0];
                float4 lo = *(const float4*)rowp;       // 16B aligned
                float2 hi = *(const float2*)(rowp + 4); // 8B aligned
                win[ci][kh][0] = lo.x; win[ci][kh][1] = lo.y;
                win[ci][kh][2] = lo.z; win[ci][kh][3] = lo.w;
                win[ci][kh][4] = hi.x; win[ci][kh][5] = hi.y;
            }

        // prefetch next plane's staging values (VMEM overlaps FMAs)
        float stv[5];
        if (t < TT - 1) {                    // uniform branch
            #pragma unroll
            for (int k = 0; k < 5; ++k) {
                stv[k] = ((svmask >> k) & 1) ? Xb[goff[k]] : 0.0f;
                goff[k] += HW;
            }
        }

        // conv: s1 = dt=1 taps on plane t; n = dt=0 taps on plane t (used at t+1)
        float s10 = bg, s11 = bg, s12 = bg, s13 = bg;
        float n0 = 0.f, n1 = 0.f, n2 = 0.f, n3 = 0.f;
        #pragma unroll
        for (int ci = 0; ci < 3; ++ci)
            #pragma unroll
            for (int kh = 0; kh < 3; ++kh)
                #pragma unroll
                for (int kw = 0; kw < 3; ++kw) {
                    const float wp = wgt[ci * 18 +     kh * 3 + kw];
                    const float wc = wgt[ci * 18 + 9 + kh * 3 + kw];
                    s10 += wc * win[ci][kh][kw + 0];
                    s11 += wc * win[ci][kh][kw + 1];
                    s12 += wc * win[ci][kh][kw + 2];
                    s13 += wc * win[ci][kh][kw + 3];
                    n0  += wp * win[ci][kh][kw + 0];
                    n1  += wp * win[ci][kh][kw + 1];
                    n2  += wp * win[ci][kh][kw + 2];
                    n3  += wp * win[ci][kh][kw + 3];
                }

        float4 gv = make_float4(s10 + s0c0, s11 + s0c1, s12 + s0c2, s13 + s0c3);
        s0c0 = n0; s0c1 = n1; s0c2 = n2; s0c3 = n3;
        *(float4*)&gbb[g * 256 + r * 64 + c0] = gv;

        // commit staged plane t+1 into the other buffer (before the barrier)
        if (t < TT - 1) {                    // uniform branch
            float* __restrict__ sxn = &sx[((t + 1) & 1) * SXSZ];
            #pragma unroll
            for (int k = 0; k < 5; ++k) sxn[soff[k]] = stv[k];
        }

        __syncthreads();   // gates(t) visible; plane t+1 committed

        // recurrence: owner thread per pixel
        const float iv = gbb[tid];
        const float fv = gbb[256 + tid];
        const float gg = gbb[512 + tid];
        const float ov = gbb[768 + tid];
        const float ig = fsigmoid(iv + wci * C);
        const float fg = fsigmoid(fv + wcf * C);
        const float Cn = fg * C + ig * ftanh(gg);
        const float og = fsigmoid(ov + wco * Cn);
        outb[ooff] = og * ftanh(Cn);
        ooff += HW;
        C = Cn;
    }
}

extern "C" void kernel_launch(void* const* d_in, const int* in_sizes, int n_in,
                              void* d_out, int out_size, void* d_ws, size_t ws_size,
                              hipStream_t stream) {
    const float* X   = (const float*)d_in[0];
    const float* Wc  = (const float*)d_in[1];
    const float* bc  = (const float*)d_in[2];
    const float* Wci = (const float*)d_in[3];
    const float* Wcf = (const float*)d_in[4];
    const float* Wco = (const float*)d_in[5];
    float* out = (float*)d_out;

    dim3 grid(16, 64, 4);   // row-tiles, cout, batch
    convqrnn<<<grid, 256, 0, stream>>>(X, Wc, bc, Wci, Wcf, Wco, out);
}

// Round 3
// 438.707 us; speedup vs baseline: 3.1973x; 1.0548x over previous
//
#include <hip/hip_runtime.h>

#define TT     32
#define HW     4096           // 64*64
#define LROW   68             // 66 cols + 2 pad -> rows 16B-aligned (b128 reads)
#define LPLANE (6 * LROW)     // 6 halo rows per cin = 408
#define SXSZ   (3 * LPLANE)   // 1224 floats per plane buffer
#define NSTG   (3 * 6 * 66)   // 1188 staged elements per plane

__device__ __forceinline__ float fsigmoid(float x) {
    return __builtin_amdgcn_rcpf(1.0f + __builtin_amdgcn_exp2f(x * -1.4426950408889634f));
}
__device__ __forceinline__ float ftanh(float x) {
    return 2.0f * __builtin_amdgcn_rcpf(1.0f + __builtin_amdgcn_exp2f(x * -2.8853900817779268f)) - 1.0f;
}
// force a wave-uniform float into an SGPR
__device__ __forceinline__ float sgprf(float v) {
    return __uint_as_float(__builtin_amdgcn_readfirstlane(__float_as_uint(v)));
}

__global__ __launch_bounds__(256, 4) void convqrnn(
    const float* __restrict__ X,    // (4,3,32,64,64)
    const float* __restrict__ Wc,   // (256,3,2,3,3)
    const float* __restrict__ bc,   // (256)
    const float* __restrict__ Wci,  // (64,64,64)
    const float* __restrict__ Wcf,
    const float* __restrict__ Wco,
    float* __restrict__ out)        // (4,64,32,64,64)
{
    __shared__ float sx[2 * SXSZ];     // double-buffered staged plane
    __shared__ float gb[2 * 2048];     // double-buffered gate exchange, 2 couts

    const int tid = threadIdx.x;
    const int h0  = blockIdx.x * 4;    // 16 row-tiles of height 4, full width
    const int co0 = blockIdx.y * 2;    // this block handles couts {co0, co0+1}
    const int b   = blockIdx.z;

    // gate-compute mapping: wave g handles gate g; lane owns 4 consecutive cols
    const int g  = tid >> 6;
    const int l  = tid & 63;
    const int r  = l >> 4;            // 0..3 tile row
    const int c0 = (l & 15) * 4;      // col base (0,4,...,60)

    // recurrence-owner mapping: pixel p = tid (4 rows x 64 cols, row-major)
    const int prow = tid >> 6;
    const int pcol = tid & 63;
    const int opix = (h0 + prow) * 64 + pcol;

    const float wciA = Wci[co0 * HW + opix];
    const float wcfA = Wcf[co0 * HW + opix];
    const float wcoA = Wco[co0 * HW + opix];
    const float wciB = Wci[(co0 + 1) * HW + opix];
    const float wcfB = Wcf[(co0 + 1) * HW + opix];
    const float wcoB = Wco[(co0 + 1) * HW + opix];

    // conv weights for (gate g, couts co0/co0+1): wave-uniform -> SGPRs
    float wgtA[54], wgtB[54];
    {
        const float* __restrict__ wrA = Wc + (size_t)(g * 64 + co0) * 54;
        const float* __restrict__ wrB = wrA + 54;
        #pragma unroll
        for (int j = 0; j < 54; ++j) wgtA[j] = sgprf(wrA[j]);
        #pragma unroll
        for (int j = 0; j < 54; ++j) wgtB[j] = sgprf(wrB[j]);
    }
    const float bgA = sgprf(bc[g * 64 + co0]);
    const float bgB = sgprf(bc[g * 64 + co0 + 1]);

    // ---- staging precompute: 5 chunks of 256 covering 3x6x66 halo tile ----
    const float* __restrict__ Xb = X + (size_t)b * (3 * TT * HW);
    int soff[5];
    int goff[5];
    int svmask = 0;
    #pragma unroll
    for (int k = 0; k < 5; ++k) {
        int idx  = tid + k * 256;
        bool inr = (idx < NSTG);
        int idc  = inr ? idx : 0;
        int ci   = idc / 396;              // 6*66
        int rem  = idc - ci * 396;
        int y    = rem / 66;
        int x    = rem - y * 66;
        int gh   = h0 + y - 1;
        int gw   = x - 1;
        bool v   = inr && (gh >= 0) && (gh < 64) && (gw >= 0) && (gw < 64);
        int ghc  = gh < 0 ? 0 : (gh > 63 ? 63 : gh);
        int gwc  = gw < 0 ? 0 : (gw > 63 ? 63 : gw);
        soff[k]  = inr ? (ci * LPLANE + y * LROW + x) : (LROW - 1); // dummy pad slot
        goff[k]  = ci * (TT * HW) + ghc * 64 + gwc;                 // plane 0
        svmask  |= (v ? 1 : 0) << k;
    }

    // prologue: stage plane t=0 into buffer 0
    #pragma unroll
    for (int k = 0; k < 5; ++k) {
        float v = ((svmask >> k) & 1) ? Xb[goff[k]] : 0.0f;
        sx[soff[k]] = v;
        goff[k] += HW;                       // -> plane 1
    }

    // output addressing (scalar base + 32-bit vector offset)
    float* __restrict__ outA = out + (size_t)(b * 64 + co0) * (TT * HW);
    float* __restrict__ outB = outA + (size_t)(TT * HW);
    int ooff = opix;

    // dt=0 partial carries, per cout
    float aA0 = 0.f, aA1 = 0.f, aA2 = 0.f, aA3 = 0.f;
    float aB0 = 0.f, aB1 = 0.f, aB2 = 0.f, aB3 = 0.f;
    float CA = 0.f, CB = 0.f;

    __syncthreads();   // plane 0 staged

    for (int t = 0; t < TT; ++t) {
        const float* __restrict__ sxb = &sx[(t & 1) * SXSZ];
        float*       __restrict__ gbb = &gb[(t & 1) * 2048];

        // window: 3 cin x 3 rows x 6 cols from LDS; two 16B-aligned b128 reads
        // (second b128 replaces the 4-way-conflicted float2; slot 67 exists)
        float win[3][3][6];
        #pragma unroll
        for (int ci = 0; ci < 3; ++ci)
            #pragma unroll
            for (int kh = 0; kh < 3; ++kh) {
                const float* rowp = &sxb[ci * LPLANE + (r + kh) * LROW + c0];
                float4 lo = *(const float4*)rowp;        // elements 0..3
                float4 hi = *(const float4*)(rowp + 4);  // elements 4..7 (6,7 unused)
                win[ci][kh][0] = lo.x; win[ci][kh][1] = lo.y;
                win[ci][kh][2] = lo.z; win[ci][kh][3] = lo.w;
                win[ci][kh][4] = hi.x; win[ci][kh][5] = hi.y;
            }

        // prefetch next plane's staging values (VMEM overlaps FMAs)
        float stv[5];
        if (t < TT - 1) {                    // uniform branch
            #pragma unroll
            for (int k = 0; k < 5; ++k) {
                stv[k] = ((svmask >> k) & 1) ? Xb[goff[k]] : 0.0f;
                goff[k] += HW;
            }
        }

        // conv: s* = dt=1 taps on plane t; n* = dt=0 taps (used at t+1)
        // two couts share the same window registers
        float sA0 = bgA, sA1 = bgA, sA2 = bgA, sA3 = bgA;
        float sB0 = bgB, sB1 = bgB, sB2 = bgB, sB3 = bgB;
        float nA0 = 0.f, nA1 = 0.f, nA2 = 0.f, nA3 = 0.f;
        float nB0 = 0.f, nB1 = 0.f, nB2 = 0.f, nB3 = 0.f;
        #pragma unroll
        for (int ci = 0; ci < 3; ++ci)
            #pragma unroll
            for (int kh = 0; kh < 3; ++kh)
                #pragma unroll
                for (int kw = 0; kw < 3; ++kw) {
                    const float w0 = win[ci][kh][kw + 0];
                    const float w1 = win[ci][kh][kw + 1];
                    const float w2 = win[ci][kh][kw + 2];
                    const float w3 = win[ci][kh][kw + 3];
                    const float wpA = wgtA[ci * 18 +     kh * 3 + kw];
                    const float wcA = wgtA[ci * 18 + 9 + kh * 3 + kw];
                    const float wpB = wgtB[ci * 18 +     kh * 3 + kw];
                    const float wcB = wgtB[ci * 18 + 9 + kh * 3 + kw];
                    sA0 += wcA * w0;  sA1 += wcA * w1;
                    sA2 += wcA * w2;  sA3 += wcA * w3;
                    nA0 += wpA * w0;  nA1 += wpA * w1;
                    nA2 += wpA * w2;  nA3 += wpA * w3;
                    sB0 += wcB * w0;  sB1 += wcB * w1;
                    sB2 += wcB * w2;  sB3 += wcB * w3;
                    nB0 += wpB * w0;  nB1 += wpB * w1;
                    nB2 += wpB * w2;  nB3 += wpB * w3;
                }

        float4 gvA = make_float4(sA0 + aA0, sA1 + aA1, sA2 + aA2, sA3 + aA3);
        float4 gvB = make_float4(sB0 + aB0, sB1 + aB1, sB2 + aB2, sB3 + aB3);
        aA0 = nA0; aA1 = nA1; aA2 = nA2; aA3 = nA3;
        aB0 = nB0; aB1 = nB1; aB2 = nB2; aB3 = nB3;
        *(float4*)&gbb[g * 256 + r * 64 + c0]        = gvA;
        *(float4*)&gbb[1024 + g * 256 + r * 64 + c0] = gvB;

        // commit staged plane t+1 into the other buffer (before the barrier)
        if (t < TT - 1) {                    // uniform branch
            float* __restrict__ sxn = &sx[((t + 1) & 1) * SXSZ];
            #pragma unroll
            for (int k = 0; k < 5; ++k) sxn[soff[k]] = stv[k];
        }

        __syncthreads();   // gates(t) visible; plane t+1 committed

        // recurrence: owner thread per pixel, both couts
        {
            const float iv = gbb[tid];
            const float fv = gbb[256 + tid];
            const float gg = gbb[512 + tid];
            const float ov = gbb[768 + tid];
            const float ig = fsigmoid(iv + wciA * CA);
            const float fg = fsigmoid(fv + wcfA * CA);
            const float Cn = fg * CA + ig * ftanh(gg);
            const float og = fsigmoid(ov + wcoA * Cn);
            outA[ooff] = og * ftanh(Cn);
            CA = Cn;
        }
        {
            const float iv = gbb[1024 + tid];
            const float fv = gbb[1024 + 256 + tid];
            const float gg = gbb[1024 + 512 + tid];
            const float ov = gbb[1024 + 768 + tid];
            const float ig = fsigmoid(iv + wciB * CB);
            const float fg = fsigmoid(fv + wcfB * CB);
            const float Cn = fg * CB + ig * ftanh(gg);
            const float og = fsigmoid(ov + wcoB * Cn);
            outB[ooff] = og * ftanh(Cn);
            CB = Cn;
        }
        ooff += HW;
    }
}

extern "C" void kernel_launch(void* const* d_in, const int* in_sizes, int n_in,
                              void* d_out, int out_size, void* d_ws, size_t ws_size,
                              hipStream_t stream) {
    const float* X   = (const float*)d_in[0];
    const float* Wc  = (const float*)d_in[1];
    const float* bc  = (const float*)d_in[2];
    const float* Wci = (const float*)d_in[3];
    const float* Wcf = (const float*)d_in[4];
    const float* Wco = (const float*)d_in[5];
    float* out = (float*)d_out;

    dim3 grid(16, 32, 4);   // row-tiles, cout-pairs, batch
    convqrnn<<<grid, 256, 0, stream>>>(X, Wc, bc, Wci, Wcf, Wco, out);
}

// Round 6
// 377.543 us; speedup vs baseline: 3.7153x; 1.1620x over previous
//
#include <hip/hip_runtime.h>

#define TT     32
#define HW     4096           // 64*64
#define LROW   68             // 66 cols + 2 pad -> rows 16B-aligned (b128 reads)
#define LPLANE (6 * LROW)     // 6 halo rows per cin = 408
#define SXSZ   (3 * LPLANE)   // 1224 floats per plane buffer
#define NSTG   (3 * 6 * 66)   // 1188 staged elements per plane

__device__ __forceinline__ float fsigmoid(float x) {
    return __builtin_amdgcn_rcpf(1.0f + __builtin_amdgcn_exp2f(x * -1.4426950408889634f));
}
__device__ __forceinline__ float ftanh(float x) {
    return 2.0f * __builtin_amdgcn_rcpf(1.0f + __builtin_amdgcn_exp2f(x * -2.8853900817779268f)) - 1.0f;
}
// force a wave-uniform float into an SGPR
__device__ __forceinline__ float sgprf(float v) {
    return __uint_as_float(__builtin_amdgcn_readfirstlane(__float_as_uint(v)));
}

__global__ __launch_bounds__(256, 2) void convqrnn(
    const float* __restrict__ X,    // (4,3,32,64,64)
    const float* __restrict__ Wc,   // (256,3,2,3,3)
    const float* __restrict__ bc,   // (256)
    const float* __restrict__ Wci,  // (64,64,64)
    const float* __restrict__ Wcf,
    const float* __restrict__ Wco,
    float* __restrict__ out)        // (4,64,32,64,64)
{
    __shared__ float sx[2 * SXSZ];     // double-buffered staged plane
    __shared__ float gb[2 * 2048];     // double-buffered gate exchange, 2 couts
    __shared__ float wl[576];          // weights: (g*9 + ci*3 + kh)*16 + which*3 + kw

    const int tid = threadIdx.x;
    const int h0  = blockIdx.x * 4;    // 16 row-tiles of height 4, full width
    const int co0 = blockIdx.y * 2;    // this block handles couts {co0, co0+1}
    const int b   = blockIdx.z;

    // gate-compute mapping: wave g handles gate g; lane owns 4 consecutive cols
    const int g  = tid >> 6;
    const int l  = tid & 63;
    const int r  = l >> 4;            // 0..3 tile row
    const int c0 = (l & 15) * 4;      // col base (0,4,...,60)

    // recurrence-owner mapping: pixel p = tid (4 rows x 64 cols, row-major)
    const int prow = tid >> 6;
    const int pcol = tid & 63;
    const int opix = (h0 + prow) * 64 + pcol;

    const float wciA = Wci[co0 * HW + opix];
    const float wcfA = Wcf[co0 * HW + opix];
    const float wcoA = Wco[co0 * HW + opix];
    const float wciB = Wci[(co0 + 1) * HW + opix];
    const float wcfB = Wcf[(co0 + 1) * HW + opix];
    const float wcoB = Wco[(co0 + 1) * HW + opix];

    // ---- cooperative fill of the LDS weight table ----
    // slot: wl[(g2*9 + ci*3 + kh)*16 + which*3 + kw]
    //   which: 0=(A,dt0) 1=(A,dt1) 2=(B,dt0) 3=(B,dt1)
    // 432 elements, 256 threads -> strided loop (round-5 bug: `if (tid<432)`
    // left groups 22..35 = gates 2/3 uninitialized)
    for (int fi = tid; fi < 432; fi += 256) {
        int grp   = fi / 12;           // 0..35 = g2*9 + ci*3+kh
        int e     = fi - grp * 12;     // 0..11 = which*3 + kw
        int g2    = grp / 9;
        int ck    = grp - g2 * 9;
        int ci    = ck / 3;
        int kh    = ck - ci * 3;
        int which = e / 3;
        int kw    = e - which * 3;
        int cs    = which >> 1;
        int dt    = which & 1;
        wl[grp * 16 + e] =
            Wc[(size_t)(g2 * 64 + co0 + cs) * 54 + ci * 18 + dt * 9 + kh * 3 + kw];
    }
    const float bgA = sgprf(bc[g * 64 + co0]);
    const float bgB = sgprf(bc[g * 64 + co0 + 1]);

    // ---- staging precompute: 5 chunks of 256 covering 3x6x66 halo tile ----
    const float* __restrict__ Xb = X + (size_t)b * (3 * TT * HW);
    int soff[5];
    int goff[5];
    int svmask = 0;
    #pragma unroll
    for (int k = 0; k < 5; ++k) {
        int idx  = tid + k * 256;
        bool inr = (idx < NSTG);
        int idc  = inr ? idx : 0;
        int ci   = idc / 396;              // 6*66
        int rem  = idc - ci * 396;
        int y    = rem / 66;
        int x    = rem - y * 66;
        int gh   = h0 + y - 1;
        int gw   = x - 1;
        bool v   = inr && (gh >= 0) && (gh < 64) && (gw >= 0) && (gw < 64);
        int ghc  = gh < 0 ? 0 : (gh > 63 ? 63 : gh);
        int gwc  = gw < 0 ? 0 : (gw > 63 ? 63 : gw);
        soff[k]  = inr ? (ci * LPLANE + y * LROW + x) : (LROW - 1); // dummy pad slot
        goff[k]  = ci * (TT * HW) + ghc * 64 + gwc;                 // plane 0
        svmask  |= (v ? 1 : 0) << k;
    }

    // prologue: stage plane t=0 into buffer 0
    #pragma unroll
    for (int k = 0; k < 5; ++k) {
        float v = ((svmask >> k) & 1) ? Xb[goff[k]] : 0.0f;
        sx[soff[k]] = v;
        goff[k] += HW;                       // -> plane 1
    }

    // output addressing (scalar base + 32-bit vector offset)
    float* __restrict__ outA = out + (size_t)(b * 64 + co0) * (TT * HW);
    float* __restrict__ outB = outA + (size_t)(TT * HW);
    int ooff = opix;

    // dt=0 partial carries, per cout
    float aA0 = 0.f, aA1 = 0.f, aA2 = 0.f, aA3 = 0.f;
    float aB0 = 0.f, aB1 = 0.f, aB2 = 0.f, aB3 = 0.f;
    float CA = 0.f, CB = 0.f;

    __syncthreads();   // plane 0 staged + weight table filled

    for (int t = 0; t < TT; ++t) {
        // never-taken uniform MayDef on wl: blocks LICM/GVN from hoisting the
        // (loop-invariant) weight loads into 108 registers. grid.x==16, so
        // this store never executes; one SALU compare per iteration.
        if (blockIdx.x == 0xFFFFFFFFu) wl[tid] = 0.0f;

        const float* __restrict__ sxb = &sx[(t & 1) * SXSZ];
        float*       __restrict__ gbb = &gb[(t & 1) * 2048];

        // prefetch next plane's staging values (VMEM overlaps FMAs)
        float stv[5];
        if (t < TT - 1) {                    // uniform branch
            #pragma unroll
            for (int k = 0; k < 5; ++k) {
                stv[k] = ((svmask >> k) & 1) ? Xb[goff[k]] : 0.0f;
                goff[k] += HW;
            }
        }

        // conv: s* = dt=1 taps on plane t; n* = dt=0 taps (used at t+1)
        float sA0 = bgA, sA1 = bgA, sA2 = bgA, sA3 = bgA;
        float sB0 = bgB, sB1 = bgB, sB2 = bgB, sB3 = bgB;
        float nA0 = 0.f, nA1 = 0.f, nA2 = 0.f, nA3 = 0.f;
        float nB0 = 0.f, nB1 = 0.f, nB2 = 0.f, nB3 = 0.f;
        #pragma unroll
        for (int ci = 0; ci < 3; ++ci)
            #pragma unroll
            for (int kh = 0; kh < 3; ++kh) {
                // window row: 6 floats (b128 + b64, 2-way banked = free)
                const float* rowp = &sxb[ci * LPLANE + (r + kh) * LROW + c0];
                float4 lo = *(const float4*)rowp;
                float2 hi = *(const float2*)(rowp + 4);
                const float w0 = lo.x, w1 = lo.y, w2 = lo.z;
                const float w3 = lo.w, w4 = hi.x, w5 = hi.y;

                // weights: 3 uniform-address b128 broadcasts, direct indexing
                const int ws = (g * 9 + ci * 3 + kh) * 16;
                float4 qa = *(const float4*)&wl[ws];      // pA0 pA1 pA2 cA0
                float4 qb = *(const float4*)&wl[ws + 4];  // cA1 cA2 pB0 pB1
                float4 qc = *(const float4*)&wl[ws + 8];  // pB2 cB0 cB1 cB2

                sA0 += qa.w * w0;  sA1 += qa.w * w1;  sA2 += qa.w * w2;  sA3 += qa.w * w3;
                sA0 += qb.x * w1;  sA1 += qb.x * w2;  sA2 += qb.x * w3;  sA3 += qb.x * w4;
                sA0 += qb.y * w2;  sA1 += qb.y * w3;  sA2 += qb.y * w4;  sA3 += qb.y * w5;

                nA0 += qa.x * w0;  nA1 += qa.x * w1;  nA2 += qa.x * w2;  nA3 += qa.x * w3;
                nA0 += qa.y * w1;  nA1 += qa.y * w2;  nA2 += qa.y * w3;  nA3 += qa.y * w4;
                nA0 += qa.z * w2;  nA1 += qa.z * w3;  nA2 += qa.z * w4;  nA3 += qa.z * w5;

                sB0 += qc.y * w0;  sB1 += qc.y * w1;  sB2 += qc.y * w2;  sB3 += qc.y * w3;
                sB0 += qc.z * w1;  sB1 += qc.z * w2;  sB2 += qc.z * w3;  sB3 += qc.z * w4;
                sB0 += qc.w * w2;  sB1 += qc.w * w3;  sB2 += qc.w * w4;  sB3 += qc.w * w5;

                nB0 += qb.z * w0;  nB1 += qb.z * w1;  nB2 += qb.z * w2;  nB3 += qb.z * w3;
                nB0 += qb.w * w1;  nB1 += qb.w * w2;  nB2 += qb.w * w3;  nB3 += qb.w * w4;
                nB0 += qc.x * w2;  nB1 += qc.x * w3;  nB2 += qc.x * w4;  nB3 += qc.x * w5;
            }

        float4 gvA = make_float4(sA0 + aA0, sA1 + aA1, sA2 + aA2, sA3 + aA3);
        float4 gvB = make_float4(sB0 + aB0, sB1 + aB1, sB2 + aB2, sB3 + aB3);
        aA0 = nA0; aA1 = nA1; aA2 = nA2; aA3 = nA3;
        aB0 = nB0; aB1 = nB1; aB2 = nB2; aB3 = nB3;
        *(float4*)&gbb[g * 256 + r * 64 + c0]        = gvA;
        *(float4*)&gbb[1024 + g * 256 + r * 64 + c0] = gvB;

        // commit staged plane t+1 into the other buffer (before the barrier)
        if (t < TT - 1) {                    // uniform branch
            float* __restrict__ sxn = &sx[((t + 1) & 1) * SXSZ];
            #pragma unroll
            for (int k = 0; k < 5; ++k) sxn[soff[k]] = stv[k];
        }

        __syncthreads();   // gates(t) visible; plane t+1 committed

        // recurrence: owner thread per pixel, both couts
        {
            const float iv = gbb[tid];
            const float fv = gbb[256 + tid];
            const float gg = gbb[512 + tid];
            const float ov = gbb[768 + tid];
            const float ig = fsigmoid(iv + wciA * CA);
            const float fg = fsigmoid(fv + wcfA * CA);
            const float Cn = fg * CA + ig * ftanh(gg);
            const float og = fsigmoid(ov + wcoA * Cn);
            outA[ooff] = og * ftanh(Cn);
            CA = Cn;
        }
        {
            const float iv = gbb[1024 + tid];
            const float fv = gbb[1024 + 256 + tid];
            const float gg = gbb[1024 + 512 + tid];
            const float ov = gbb[1024 + 768 + tid];
            const float ig = fsigmoid(iv + wciB * CB);
            const float fg = fsigmoid(fv + wcfB * CB);
            const float Cn = fg * CB + ig * ftanh(gg);
            const float og = fsigmoid(ov + wcoB * Cn);
            outB[ooff] = og * ftanh(Cn);
            CB = Cn;
        }
        ooff += HW;
    }
}

extern "C" void kernel_launch(void* const* d_in, const int* in_sizes, int n_in,
                              void* d_out, int out_size, void* d_ws, size_t ws_size,
                              hipStream_t stream) {
    const float* X   = (const float*)d_in[0];
    const float* Wc  = (const float*)d_in[1];
    const float* bc  = (const float*)d_in[2];
    const float* Wci = (const float*)d_in[3];
    const float* Wcf = (const float*)d_in[4];
    const float* Wco = (const float*)d_in[5];
    float* out = (float*)d_out;

    dim3 grid(16, 32, 4);   // row-tiles, cout-pairs, batch
    convqrnn<<<grid, 256, 0, stream>>>(X, Wc, bc, Wci, Wcf, Wco, out);
}